// Round 1
// baseline (728.123 us; speedup 1.0000x reference)
//
#include <hip/hip_runtime.h>
#include <math.h>

#define BATCH 4
#define SEQ   4096
#define EMB   1024
#define HD    128
#define QSCALE 0.08838834764831845f  // 1/sqrt(128)

// ============================ projection GEMM ============================
// y[m][a] = sum_e x[m][e] * W[a][e]
// tile 128(M) x 64(N), BK=32, 256 threads, 8x4 per thread.
// tx = tid&15 -> cols n0 + tx + 16j (j<4); ty = tid>>4 -> rows ty*8+i (i<8)
#define PJ_BM 128
#define PJ_BN 64
#define PJ_BK 32

__global__ __launch_bounds__(256, 2) void proj_kernel(
    const float* __restrict__ X,
    const float* __restrict__ Wq, const float* __restrict__ Wk, const float* __restrict__ Wv,
    float* __restrict__ Qo, float* __restrict__ Ko, float* __restrict__ Vo)
{
    __shared__ float Xst[PJ_BK][PJ_BM + 4];   // [kk][row]  32 x 132
    __shared__ float Wst[PJ_BN][PJ_BK + 4];   // [col][kk]  64 x 36

    const int tid = threadIdx.x;
    const int tx = tid & 15, ty = tid >> 4;
    const int m0 = blockIdx.x * PJ_BM;
    const int wsel = blockIdx.y >> 1;            // 0:Q 1:K 2:V
    const int n0 = (blockIdx.y & 1) * PJ_BN;
    const float* W = (wsel == 0) ? Wq : (wsel == 1 ? Wk : Wv);
    float* Y       = (wsel == 0) ? Qo : (wsel == 1 ? Ko : Vo);

    float acc[8][4];
#pragma unroll
    for (int i = 0; i < 8; ++i)
#pragma unroll
        for (int j = 0; j < 4; ++j) acc[i][j] = 0.f;

    for (int k0 = 0; k0 < EMB; k0 += PJ_BK) {
        // stage X tile 128x32 (transposed into LDS): 1024 float4 loads
#pragma unroll
        for (int i = 0; i < 4; ++i) {
            int f = tid + 256 * i;
            int row = f >> 3, c4 = f & 7;
            float4 v = *(const float4*)&X[(size_t)(m0 + row) * EMB + k0 + 4 * c4];
            Xst[4 * c4 + 0][row] = v.x;
            Xst[4 * c4 + 1][row] = v.y;
            Xst[4 * c4 + 2][row] = v.z;
            Xst[4 * c4 + 3][row] = v.w;
        }
        // stage W tile 64x32: 512 float4
#pragma unroll
        for (int i = 0; i < 2; ++i) {
            int f = tid + 256 * i;
            int col = f >> 3, c4 = f & 7;
            float4 v = *(const float4*)&W[(size_t)(n0 + col) * EMB + k0 + 4 * c4];
            *(float4*)&Wst[col][4 * c4] = v;
        }
        __syncthreads();

#pragma unroll
        for (int kk4 = 0; kk4 < PJ_BK / 4; ++kk4) {
            float4 b4[4];
#pragma unroll
            for (int j = 0; j < 4; ++j)
                b4[j] = *(const float4*)&Wst[tx + 16 * j][4 * kk4];
#pragma unroll
            for (int jj = 0; jj < 4; ++jj) {
                const int kk = 4 * kk4 + jj;
                const float4 a0 = *(const float4*)&Xst[kk][ty * 8];
                const float4 a1 = *(const float4*)&Xst[kk][ty * 8 + 4];
                const float av[8] = {a0.x, a0.y, a0.z, a0.w, a1.x, a1.y, a1.z, a1.w};
#pragma unroll
                for (int j = 0; j < 4; ++j) {
                    const float bj = ((const float*)&b4[j])[jj];
#pragma unroll
                    for (int i = 0; i < 8; ++i) acc[i][j] = fmaf(av[i], bj, acc[i][j]);
                }
            }
        }
        __syncthreads();
    }

#pragma unroll
    for (int i = 0; i < 8; ++i) {
        size_t rowoff = (size_t)(m0 + ty * 8 + i) * HD + n0;
#pragma unroll
        for (int j = 0; j < 4; ++j) Y[rowoff + tx + 16 * j] = acc[i][j];
    }
}

// ============================ flash attention (fp32) ============================
// BQ=BK=64, 256 threads. Scores 4x4/thread (rows ty*4+i, cols tx+16c).
// O 4x8/thread (cols tx+16j, j<8). Each block does HALF the k-range of one
// q-tile (split-2 for causal load balance); partials merged by merge_kernel.
#define AT_BQ 64
#define AT_BK 64

__global__ __launch_bounds__(256, 1) void attn_kernel(
    const float* __restrict__ Q, const float* __restrict__ K, const float* __restrict__ V,
    float* __restrict__ Opart, float* __restrict__ MLpart)
{
    __shared__ float Qs[AT_BQ][HD + 4];      // 64 x 132
    __shared__ float Ks[AT_BK][HD + 4];      // 64 x 132
    __shared__ float Vst[HD][AT_BK + 4];     // 128 x 68  (V transposed: [col][s])
    __shared__ float Ps[AT_BQ][AT_BK + 4];   // 64 x 68

    const int pid = blockIdx.x;
    const int qprime = pid >> 3;             // 0..63, descending work size
    const int b = (pid >> 1) & 3;
    const int half = pid & 1;
    const int qt = 63 - qprime;

    const int tid = threadIdx.x, tx = tid & 15, ty = tid >> 4;
    const size_t bbase = (size_t)b * SEQ * HD;
    const int q0 = qt * AT_BQ;
    const int nk = qt + 1;                   // k-tiles in causal range
    const int kb = half ? nk / 2 : 0;
    const int ke = half ? nk : nk / 2;

    // stage Q (pre-scaled); first in-loop barrier covers visibility
#pragma unroll
    for (int i = 0; i < 8; ++i) {
        int f = tid + 256 * i;
        int r = f >> 5, c4 = f & 31;
        float4 v = *(const float4*)&Q[bbase + (size_t)(q0 + r) * HD + 4 * c4];
        v.x *= QSCALE; v.y *= QSCALE; v.z *= QSCALE; v.w *= QSCALE;
        *(float4*)&Qs[r][4 * c4] = v;
    }

    float m[4], l[4], o[4][8];
#pragma unroll
    for (int i = 0; i < 4; ++i) {
        m[i] = -1e30f; l[i] = 0.f;
#pragma unroll
        for (int j = 0; j < 8; ++j) o[i][j] = 0.f;
    }

    for (int kt = kb; kt < ke; ++kt) {
        const int kr0 = kt * AT_BK;
        // stage K tile (row-major)
#pragma unroll
        for (int i = 0; i < 8; ++i) {
            int f = tid + 256 * i;
            int r = f >> 5, c4 = f & 31;
            *(float4*)&Ks[r][4 * c4] =
                *(const float4*)&K[bbase + (size_t)(kr0 + r) * HD + 4 * c4];
        }
        // stage V tile transposed [col][s]
#pragma unroll
        for (int i = 0; i < 8; ++i) {
            int f = tid + 256 * i;
            int s = f >> 5, c4 = f & 31;
            float4 v = *(const float4*)&V[bbase + (size_t)(kr0 + s) * HD + 4 * c4];
            Vst[4 * c4 + 0][s] = v.x;
            Vst[4 * c4 + 1][s] = v.y;
            Vst[4 * c4 + 2][s] = v.z;
            Vst[4 * c4 + 3][s] = v.w;
        }
        __syncthreads();

        // QK^T -> sc[4][4]
        float sc[4][4];
#pragma unroll
        for (int i = 0; i < 4; ++i)
#pragma unroll
            for (int c = 0; c < 4; ++c) sc[i][c] = 0.f;

#pragma unroll
        for (int d4 = 0; d4 < HD / 4; ++d4) {
            float4 kv[4];
#pragma unroll
            for (int c = 0; c < 4; ++c)
                kv[c] = *(const float4*)&Ks[tx + 16 * c][4 * d4];
#pragma unroll
            for (int i = 0; i < 4; ++i) {
                const float4 qv = *(const float4*)&Qs[ty * 4 + i][4 * d4];
#pragma unroll
                for (int c = 0; c < 4; ++c) {
                    sc[i][c] = fmaf(qv.x, kv[c].x, sc[i][c]);
                    sc[i][c] = fmaf(qv.y, kv[c].y, sc[i][c]);
                    sc[i][c] = fmaf(qv.z, kv[c].z, sc[i][c]);
                    sc[i][c] = fmaf(qv.w, kv[c].w, sc[i][c]);
                }
            }
        }

        // causal mask on diagonal tile
        if (kt == qt) {
#pragma unroll
            for (int i = 0; i < 4; ++i) {
                const int qg = q0 + ty * 4 + i;
#pragma unroll
                for (int c = 0; c < 4; ++c) {
                    const int cg = kr0 + tx + 16 * c;
                    if (cg > qg) sc[i][c] = -1e30f;
                }
            }
        }

        // online softmax (row reduce over the 16 tx lanes)
#pragma unroll
        for (int i = 0; i < 4; ++i) {
            float rm = fmaxf(fmaxf(sc[i][0], sc[i][1]), fmaxf(sc[i][2], sc[i][3]));
#pragma unroll
            for (int off = 1; off < 16; off <<= 1) rm = fmaxf(rm, __shfl_xor(rm, off));
            const float mn = fmaxf(m[i], rm);
            const float corr = __expf(m[i] - mn);
            float p[4], rs = 0.f;
#pragma unroll
            for (int c = 0; c < 4; ++c) { p[c] = __expf(sc[i][c] - mn); rs += p[c]; }
#pragma unroll
            for (int off = 1; off < 16; off <<= 1) rs += __shfl_xor(rs, off);
            l[i] = l[i] * corr + rs;
            m[i] = mn;
#pragma unroll
            for (int j = 0; j < 8; ++j) o[i][j] *= corr;
#pragma unroll
            for (int c = 0; c < 4; ++c) Ps[ty * 4 + i][tx + 16 * c] = p[c];
        }
        __syncthreads();

        // PV: o += P @ V   (reads Ps rows b128, Vst cols b128-over-s)
#pragma unroll
        for (int s4 = 0; s4 < AT_BK / 4; ++s4) {
            float4 vv[8];
#pragma unroll
            for (int j = 0; j < 8; ++j)
                vv[j] = *(const float4*)&Vst[tx + 16 * j][4 * s4];
#pragma unroll
            for (int i = 0; i < 4; ++i) {
                const float4 pa = *(const float4*)&Ps[ty * 4 + i][4 * s4];
#pragma unroll
                for (int j = 0; j < 8; ++j) {
                    o[i][j] = fmaf(pa.x, vv[j].x, o[i][j]);
                    o[i][j] = fmaf(pa.y, vv[j].y, o[i][j]);
                    o[i][j] = fmaf(pa.z, vv[j].z, o[i][j]);
                    o[i][j] = fmaf(pa.w, vv[j].w, o[i][j]);
                }
            }
        }
        __syncthreads();
    }

    // write partial (unnormalized O, running m, l)
#pragma unroll
    for (int i = 0; i < 4; ++i) {
        const int r = ty * 4 + i;
        const size_t obase = ((size_t)pid * AT_BQ + r) * HD;
#pragma unroll
        for (int j = 0; j < 8; ++j) Opart[obase + tx + 16 * j] = o[i][j];
        if (tx == 0) {
            MLpart[(pid * AT_BQ + r) * 2 + 0] = m[i];
            MLpart[(pid * AT_BQ + r) * 2 + 1] = l[i];
        }
    }
}

// ============================ merge partials ============================
__global__ __launch_bounds__(256) void merge_kernel(
    const float* __restrict__ Opart, const float* __restrict__ MLpart,
    float* __restrict__ out)
{
    const int idx = blockIdx.x * 256 + threadIdx.x;    // float4 index, 524288 total
    const int col4 = idx & 31;
    const int row = idx >> 5;                          // 0..65535 over B*T
    const int b = row >> 12;
    const int t = row & 4095;
    const int qt = t >> 6;
    const int r = t & 63;
    const int qp = 63 - qt;
    const int pid0 = qp * 8 + b * 2 + 0;
    const int pid1 = pid0 + 1;

    const float m0 = MLpart[(pid0 * 64 + r) * 2 + 0];
    const float l0 = MLpart[(pid0 * 64 + r) * 2 + 1];
    const float m1 = MLpart[(pid1 * 64 + r) * 2 + 0];
    const float l1 = MLpart[(pid1 * 64 + r) * 2 + 1];
    const float mm = fmaxf(m0, m1);
    const float w0 = __expf(m0 - mm);
    const float w1 = __expf(m1 - mm);
    const float inv = 1.0f / (l0 * w0 + l1 * w1);

    const float4 o0 = *(const float4*)&Opart[((size_t)pid0 * 64 + r) * HD + 4 * col4];
    const float4 o1 = *(const float4*)&Opart[((size_t)pid1 * 64 + r) * HD + 4 * col4];
    float4 res;
    res.x = (o0.x * w0 + o1.x * w1) * inv;
    res.y = (o0.y * w0 + o1.y * w1) * inv;
    res.z = (o0.z * w0 + o1.z * w1) * inv;
    res.w = (o0.w * w0 + o1.w * w1) * inv;
    *(float4*)&out[(size_t)row * HD + 4 * col4] = res;
}

// ============================ launch ============================
extern "C" void kernel_launch(void* const* d_in, const int* in_sizes, int n_in,
                              void* d_out, int out_size, void* d_ws, size_t ws_size,
                              hipStream_t stream) {
    const float* X  = (const float*)d_in[0];
    const float* Wk = (const float*)d_in[1];
    const float* Wq = (const float*)d_in[2];
    const float* Wv = (const float*)d_in[3];
    float* out = (float*)d_out;

    float* ws = (float*)d_ws;
    const size_t NQKV = (size_t)BATCH * SEQ * HD;      // 2,097,152
    float* Qb = ws;
    float* Kb = Qb + NQKV;
    float* Vb = Kb + NQKV;
    float* Opart  = Vb + NQKV;                         // 512*64*128 = 4,194,304
    float* MLpart = Opart + (size_t)512 * 64 * HD;     // 65,536
    (void)in_sizes; (void)n_in; (void)out_size; (void)ws_size;

    proj_kernel<<<dim3(BATCH * SEQ / PJ_BM, 6), 256, 0, stream>>>(X, Wq, Wk, Wv, Qb, Kb, Vb);
    attn_kernel<<<dim3(512), 256, 0, stream>>>(Qb, Kb, Vb, Opart, MLpart);
    merge_kernel<<<dim3((BATCH * SEQ * HD / 4) / 256), 256, 0, stream>>>(Opart, MLpart, out);
}

// Round 5
// 273.306 us; speedup vs baseline: 2.6641x; 2.6641x over previous
//
#include <hip/hip_runtime.h>
#include <math.h>

#define BATCH 4
#define SEQ   4096
#define EMB   1024
#define HD    128
#define QSCALE 0.08838834764831845f  // 1/sqrt(128)

typedef __bf16 bf16x8 __attribute__((ext_vector_type(8)));
typedef __bf16 bf16x4 __attribute__((ext_vector_type(4)));
typedef float  f32x4  __attribute__((ext_vector_type(4)));

#define MFMA16(a,b,c) __builtin_amdgcn_mfma_f32_16x16x32_bf16((a),(b),(c),0,0,0)

// proj LDS row pitch: 40 bf16 (80 B) so 16-row b128 frag reads are 2-way (free)
#define PJP 40

// ============================ hi/lo split of weights ============================
__global__ __launch_bounds__(256) void split_kernel(
    const float* __restrict__ src, __bf16* __restrict__ hi, __bf16* __restrict__ lo,
    float scale, int n4)
{
    int i = blockIdx.x * 256 + threadIdx.x;
    if (i >= n4) return;
    float4 v = ((const float4*)src)[i];
    float vv[4] = {v.x * scale, v.y * scale, v.z * scale, v.w * scale};
    bf16x4 h, l;
#pragma unroll
    for (int j = 0; j < 4; ++j) {
        __bf16 hh = (__bf16)vv[j];
        h[j] = hh;
        l[j] = (__bf16)(vv[j] - (float)hh);
    }
    *(bf16x4*)&hi[i * 4] = h;
    *(bf16x4*)&lo[i * 4] = l;
}

// ============================ projection GEMM (MFMA, split-3) ============================
// Y[m][a] = sum_e X[m][e] * W[a][e];  128x128 tile, BK=32, 4 waves (2x2), 64x64/wave.
// Q/K outputs written as hi/lo bf16 pairs; V written transposed VT[b][a][t] hi/lo.
__global__ __launch_bounds__(256) void proj_mfma(
    const float* __restrict__ X,
    const __bf16* __restrict__ Wqh, const __bf16* __restrict__ Wql,
    const __bf16* __restrict__ Wkh, const __bf16* __restrict__ Wkl,
    const __bf16* __restrict__ Wvh, const __bf16* __restrict__ Wvl,
    __bf16* __restrict__ Qh, __bf16* __restrict__ Ql,
    __bf16* __restrict__ Kh, __bf16* __restrict__ Kl,
    __bf16* __restrict__ VTh, __bf16* __restrict__ VTl)
{
    __shared__ __align__(16) __bf16 Ah[128 * PJP], Al[128 * PJP];
    __shared__ __align__(16) __bf16 Bh[128 * PJP], Bl[128 * PJP];

    const int tid = threadIdx.x;
    const int lane = tid & 63, wid = tid >> 6;
    const int l15 = lane & 15, l4 = lane >> 4;
    const int wm = wid >> 1, wn = wid & 1;
    const int m0 = blockIdx.x * 128;
    const int wsel = blockIdx.y;                 // 0:Q 1:K 2:V
    const __bf16* Wh = (wsel == 0) ? Wqh : (wsel == 1 ? Wkh : Wvh);
    const __bf16* Wl = (wsel == 0) ? Wql : (wsel == 1 ? Wkl : Wvl);

    f32x4 acc[4][4];
    const f32x4 z4 = {0.f, 0.f, 0.f, 0.f};
#pragma unroll
    for (int fi = 0; fi < 4; ++fi)
#pragma unroll
        for (int fj = 0; fj < 4; ++fj) acc[fi][fj] = z4;

    for (int k0 = 0; k0 < EMB; k0 += 32) {
        // stage X (fp32 -> hi/lo bf16), tile 128x32, [row][k] layout (80 B pitch)
#pragma unroll
        for (int i = 0; i < 4; ++i) {
            int e4 = tid + 256 * i;
            int row = e4 >> 3, c4 = e4 & 7;
            float4 v = *(const float4*)&X[(m0 + row) * EMB + k0 + c4 * 4];
            float vv[4] = {v.x, v.y, v.z, v.w};
            bf16x4 h, l;
#pragma unroll
            for (int j = 0; j < 4; ++j) {
                __bf16 hh = (__bf16)vv[j];
                h[j] = hh;
                l[j] = (__bf16)(vv[j] - (float)hh);
            }
            *(bf16x4*)&Ah[row * PJP + c4 * 4] = h;
            *(bf16x4*)&Al[row * PJP + c4 * 4] = l;
        }
        // stage W tiles (already bf16 hi/lo), 128x32
#pragma unroll
        for (int i = 0; i < 2; ++i) {
            int s = tid + 256 * i;
            int row = s >> 2, ko8 = s & 3;
            *(uint4*)&Bh[row * PJP + ko8 * 8] = *(const uint4*)&Wh[row * EMB + k0 + ko8 * 8];
            *(uint4*)&Bl[row * PJP + ko8 * 8] = *(const uint4*)&Wl[row * EMB + k0 + ko8 * 8];
        }
        __syncthreads();

        bf16x8 ah[4], al[4], bh[4], bl[4];
#pragma unroll
        for (int f = 0; f < 4; ++f) {
            int arow = wm * 64 + f * 16 + l15;
            ah[f] = *(const bf16x8*)&Ah[arow * PJP + l4 * 8];
            al[f] = *(const bf16x8*)&Al[arow * PJP + l4 * 8];
            int bcol = wn * 64 + f * 16 + l15;
            bh[f] = *(const bf16x8*)&Bh[bcol * PJP + l4 * 8];
            bl[f] = *(const bf16x8*)&Bl[bcol * PJP + l4 * 8];
        }
#pragma unroll
        for (int fi = 0; fi < 4; ++fi)
#pragma unroll
            for (int fj = 0; fj < 4; ++fj) {
                acc[fi][fj] = MFMA16(ah[fi], bh[fj], acc[fi][fj]);
                acc[fi][fj] = MFMA16(al[fi], bh[fj], acc[fi][fj]);
                acc[fi][fj] = MFMA16(ah[fi], bl[fj], acc[fi][fj]);
            }
        __syncthreads();
    }

    // epilogue: C row = (l>>4)*4+r, col = l&15 within each 16x16 frag [m89]
    if (wsel < 2) {
        __bf16* Yh = (wsel == 0) ? Qh : Kh;
        __bf16* Yl = (wsel == 0) ? Ql : Kl;
#pragma unroll
        for (int fi = 0; fi < 4; ++fi)
#pragma unroll
            for (int fj = 0; fj < 4; ++fj) {
                int col = wn * 64 + fj * 16 + l15;
#pragma unroll
                for (int r = 0; r < 4; ++r) {
                    int row = m0 + wm * 64 + fi * 16 + l4 * 4 + r;
                    float y = acc[fi][fj][r];
                    __bf16 hh = (__bf16)y;
                    Yh[row * HD + col] = hh;
                    Yl[row * HD + col] = (__bf16)(y - (float)hh);
                }
            }
    } else {
#pragma unroll
        for (int fi = 0; fi < 4; ++fi)
#pragma unroll
            for (int fj = 0; fj < 4; ++fj) {
                int col = wn * 64 + fj * 16 + l15;
                int row0 = m0 + wm * 64 + fi * 16 + l4 * 4;
                int bb = row0 >> 12, t0 = row0 & 4095;
                bf16x4 h4, l4v;
#pragma unroll
                for (int r = 0; r < 4; ++r) {
                    float y = acc[fi][fj][r];
                    __bf16 hh = (__bf16)y;
                    h4[r] = hh;
                    l4v[r] = (__bf16)(y - (float)hh);
                }
                int off = (bb * HD + col) * SEQ + t0;
                *(bf16x4*)&VTh[off] = h4;
                *(bf16x4*)&VTl[off] = l4v;
            }
    }
}

// ============================ flash attention (MFMA, split) ============================
// BQ=64 (4 waves x 16 rows), BKV=64. QK^T split-3, PV split-3 (Phi/Plo x Vhi/Vlo, drop lo*lo).
// XOR-swizzled LDS (16B-slot index ^= row&7) for conflict-free ds_read_b128.
__global__ __launch_bounds__(256) void attn_mfma(
    const __bf16* __restrict__ Qh, const __bf16* __restrict__ Ql,
    const __bf16* __restrict__ Kh, const __bf16* __restrict__ Kl,
    const __bf16* __restrict__ VTh, const __bf16* __restrict__ VTl,
    float* __restrict__ Opart, float* __restrict__ MLpart)
{
    __shared__ __align__(16) __bf16 KhS[64 * 128], KlS[64 * 128];   // [kj][d] swizzled
    __shared__ __align__(16) __bf16 VhS[128 * 64], VlS[128 * 64];   // [vd][s] swizzled
    __shared__ __align__(16) __bf16 PhS[64 * 64],  PlS[64 * 64];    // [q][s]  swizzled

    const int pid = blockIdx.x;
    const int qt = 63 - (pid >> 3);
    const int b = (pid >> 1) & 3;
    const int half = pid & 1;
    const int tid = threadIdx.x;
    const int lane = tid & 63, wv = tid >> 6;
    const int l15 = lane & 15, l4 = lane >> 4;
    const int q0 = qt * 64;
    const int nk = qt + 1;
    const int kb = half ? nk / 2 : 0;
    const int ke = half ? nk : nk / 2;

    // Q fragments held in registers for the whole block (K=128 -> 4 d-steps, hi+lo)
    bf16x8 qh[4], ql[4];
    {
        int qrow = b * SEQ + q0 + wv * 16 + l15;
#pragma unroll
        for (int ds = 0; ds < 4; ++ds) {
            qh[ds] = *(const bf16x8*)&Qh[qrow * HD + ds * 32 + l4 * 8];
            ql[ds] = *(const bf16x8*)&Ql[qrow * HD + ds * 32 + l4 * 8];
        }
    }

    float m[4], lsum[4];
    f32x4 acc[8];
    const f32x4 z4 = {0.f, 0.f, 0.f, 0.f};
#pragma unroll
    for (int r = 0; r < 4; ++r) { m[r] = -1e30f; lsum[r] = 0.f; }
#pragma unroll
    for (int df = 0; df < 8; ++df) acc[df] = z4;

    for (int kt = kb; kt < ke; ++kt) {
        const int kv0 = kt * 64;
        __syncthreads();   // previous tile's LDS reads complete before restage
        {
            // K tiles: 64 rows x 16 slots of 8 bf16; stored slot sko holds dblk = sko^(kj&7)
            int kvbase = (b * SEQ + kv0) * HD;
#pragma unroll
            for (int i = 0; i < 4; ++i) {
                int s = tid + 256 * i;
                int kj = s >> 4, sko = s & 15;
                int dblk = sko ^ (kj & 7);
                int g = kvbase + kj * HD + dblk * 8;
                *(uint4*)&KhS[kj * 128 + sko * 8] = *(const uint4*)&Kh[g];
                *(uint4*)&KlS[kj * 128 + sko * 8] = *(const uint4*)&Kl[g];
            }
            // VT tiles: 128 rows x 8 slots of 8 bf16
            int vtb = b * HD * SEQ;
#pragma unroll
            for (int i = 0; i < 4; ++i) {
                int s = tid + 256 * i;
                int vr = s >> 3, sko = s & 7;
                int dblk = sko ^ (vr & 7);
                int g = vtb + vr * SEQ + kv0 + dblk * 8;
                *(uint4*)&VhS[vr * 64 + sko * 8] = *(const uint4*)&VTh[g];
                *(uint4*)&VlS[vr * 64 + sko * 8] = *(const uint4*)&VTl[g];
            }
        }
        __syncthreads();

        // QK^T: S[16 x 64] per wave, 4 col-frags
        f32x4 sc[4];
#pragma unroll
        for (int c = 0; c < 4; ++c) sc[c] = z4;
#pragma unroll
        for (int ds = 0; ds < 4; ++ds) {
#pragma unroll
            for (int c = 0; c < 4; ++c) {
                int kj = l15 + 16 * c;
                int koL = ds * 4 + l4;
                int eoff = kj * 128 + ((koL ^ (kj & 7)) * 8);
                bf16x8 bh = *(const bf16x8*)&KhS[eoff];
                bf16x8 bl = *(const bf16x8*)&KlS[eoff];
                sc[c] = MFMA16(qh[ds], bh, sc[c]);
                sc[c] = MFMA16(ql[ds], bh, sc[c]);
                sc[c] = MFMA16(qh[ds], bl, sc[c]);
            }
        }

        // causal mask on the diagonal tile
        if (kt == qt) {
#pragma unroll
            for (int c = 0; c < 4; ++c) {
                int cg = kv0 + l15 + 16 * c;
#pragma unroll
                for (int r = 0; r < 4; ++r) {
                    int rg = q0 + wv * 16 + l4 * 4 + r;
                    if (cg > rg) sc[c][r] = -1e30f;
                }
            }
        }

        // online softmax (reduce across the 16 l15 lanes) + P hi/lo -> LDS (wave-private rows)
#pragma unroll
        for (int r = 0; r < 4; ++r) {
            float rm = fmaxf(fmaxf(sc[0][r], sc[1][r]), fmaxf(sc[2][r], sc[3][r]));
#pragma unroll
            for (int off = 1; off < 16; off <<= 1) rm = fmaxf(rm, __shfl_xor(rm, off));
            float mn = fmaxf(m[r], rm);
            float corr = __expf(m[r] - mn);
            float p[4], rs = 0.f;
#pragma unroll
            for (int c = 0; c < 4; ++c) { p[c] = __expf(sc[c][r] - mn); rs += p[c]; }
#pragma unroll
            for (int off = 1; off < 16; off <<= 1) rs += __shfl_xor(rs, off);
            lsum[r] = lsum[r] * corr + rs;
            m[r] = mn;
#pragma unroll
            for (int df = 0; df < 8; ++df) acc[df][r] *= corr;
            int row = wv * 16 + l4 * 4 + r;
#pragma unroll
            for (int c = 0; c < 4; ++c) {
                int col = l15 + 16 * c;
                int eoff = row * 64 + (((col >> 3) ^ (row & 7)) * 8) + (col & 7);
                __bf16 ph = (__bf16)p[c];
                PhS[eoff] = ph;
                PlS[eoff] = (__bf16)(p[c] - (float)ph);
            }
        }

        // PV: O[16 x 128] per wave; a-frags from wave-private P rows (no barrier needed)
#pragma unroll
        for (int ks = 0; ks < 2; ++ks) {
            int prow = wv * 16 + l15;
            int peoff = prow * 64 + (((ks * 4 + l4) ^ (prow & 7)) * 8);
            bf16x8 pah = *(const bf16x8*)&PhS[peoff];
            bf16x8 pal = *(const bf16x8*)&PlS[peoff];
#pragma unroll
            for (int df = 0; df < 8; ++df) {
                int vr = l15 + 16 * df;
                int veoff = vr * 64 + (((ks * 4 + l4) ^ (vr & 7)) * 8);
                bf16x8 vh = *(const bf16x8*)&VhS[veoff];
                bf16x8 vl = *(const bf16x8*)&VlS[veoff];
                acc[df] = MFMA16(pah, vh, acc[df]);
                acc[df] = MFMA16(pal, vh, acc[df]);
                acc[df] = MFMA16(pah, vl, acc[df]);
            }
        }
    }

    // write partial (unnormalized O, running m, l)
#pragma unroll
    for (int df = 0; df < 8; ++df)
#pragma unroll
        for (int r = 0; r < 4; ++r) {
            int row = wv * 16 + l4 * 4 + r;
            Opart[(pid * 64 + row) * HD + l15 + 16 * df] = acc[df][r];
        }
    if (l15 == 0) {
#pragma unroll
        for (int r = 0; r < 4; ++r) {
            int row = wv * 16 + l4 * 4 + r;
            MLpart[(pid * 64 + row) * 2 + 0] = m[r];
            MLpart[(pid * 64 + row) * 2 + 1] = lsum[r];
        }
    }
}

// ============================ merge partials ============================
__global__ __launch_bounds__(256) void merge_kernel(
    const float* __restrict__ Opart, const float* __restrict__ MLpart,
    float* __restrict__ out)
{
    const int idx = blockIdx.x * 256 + threadIdx.x;    // float4 index
    const int col4 = idx & 31;
    const int row = idx >> 5;                          // 0..65535 over B*T
    const int t = row & 4095;
    const int qt = t >> 6;
    const int r = t & 63;
    const int b = row >> 12;
    const int qp = 63 - qt;
    const int pid0 = qp * 8 + b * 2 + 0;
    const int pid1 = pid0 + 1;

    const float m0 = MLpart[(pid0 * 64 + r) * 2 + 0];
    const float l0 = MLpart[(pid0 * 64 + r) * 2 + 1];
    const float m1 = MLpart[(pid1 * 64 + r) * 2 + 0];
    const float l1 = MLpart[(pid1 * 64 + r) * 2 + 1];
    const float mm = fmaxf(m0, m1);
    const float w0 = __expf(m0 - mm);
    const float w1 = __expf(m1 - mm);
    const float inv = 1.0f / (l0 * w0 + l1 * w1);

    const float4 o0 = *(const float4*)&Opart[((size_t)pid0 * 64 + r) * HD + 4 * col4];
    const float4 o1 = *(const float4*)&Opart[((size_t)pid1 * 64 + r) * HD + 4 * col4];
    float4 res;
    res.x = (o0.x * w0 + o1.x * w1) * inv;
    res.y = (o0.y * w0 + o1.y * w1) * inv;
    res.z = (o0.z * w0 + o1.z * w1) * inv;
    res.w = (o0.w * w0 + o1.w * w1) * inv;
    *(float4*)&out[(size_t)row * HD + 4 * col4] = res;
}

// ============================ launch ============================
extern "C" void kernel_launch(void* const* d_in, const int* in_sizes, int n_in,
                              void* d_out, int out_size, void* d_ws, size_t ws_size,
                              hipStream_t stream) {
    const float* X  = (const float*)d_in[0];
    const float* Wk = (const float*)d_in[1];
    const float* Wq = (const float*)d_in[2];
    const float* Wv = (const float*)d_in[3];
    float* out = (float*)d_out;
    char* wsb = (char*)d_ws;
    (void)in_sizes; (void)n_in; (void)out_size; (void)ws_size;

    const size_t MB4 = 4194304;   // bytes of one [16384][128] bf16 array
    __bf16* Qh  = (__bf16*)(wsb + 0 * MB4);
    __bf16* Ql  = (__bf16*)(wsb + 1 * MB4);
    __bf16* Kh  = (__bf16*)(wsb + 2 * MB4);
    __bf16* Kl  = (__bf16*)(wsb + 3 * MB4);
    __bf16* VTh = (__bf16*)(wsb + 4 * MB4);
    __bf16* VTl = (__bf16*)(wsb + 5 * MB4);
    float* Opart  = (float*)(wsb + 6 * MB4);                 // 16 MB
    float* MLpart = (float*)(wsb + 6 * MB4 + 16777216);      // 256 KB
    // W hi/lo splits alias the Opart region (dead by the time attn writes Opart)
    __bf16* Wqh = (__bf16*)(wsb + 6 * MB4);
    __bf16* Wql = Wqh + 131072;
    __bf16* Wkh = Wql + 131072;
    __bf16* Wkl = Wkh + 131072;
    __bf16* Wvh = Wkl + 131072;
    __bf16* Wvl = Wvh + 131072;

    split_kernel<<<128, 256, 0, stream>>>(Wq, Wqh, Wql, QSCALE, 32768);
    split_kernel<<<128, 256, 0, stream>>>(Wk, Wkh, Wkl, 1.0f, 32768);
    split_kernel<<<128, 256, 0, stream>>>(Wv, Wvh, Wvl, 1.0f, 32768);
    proj_mfma<<<dim3(128, 3), 256, 0, stream>>>(X, Wqh, Wql, Wkh, Wkl, Wvh, Wvl,
                                                Qh, Ql, Kh, Kl, VTh, VTl);
    attn_mfma<<<512, 256, 0, stream>>>(Qh, Ql, Kh, Kl, VTh, VTl, Opart, MLpart);
    merge_kernel<<<2048, 256, 0, stream>>>(Opart, MLpart, out);
}